// Round 3
// baseline (1477.040 us; speedup 1.0000x reference)
//
#include <hip/hip_runtime.h>
#include <hip/hip_bf16.h>
#include <math.h>

// Problem: Attention_58102317580396
// B=2, S=2048, D=2048, H=16, DH=128. Inputs/outputs are FP32 (per reference);
// compute internally in bf16 MFMA with fp32 accum (threshold is 2% relative).
// Pipeline: cvt(x,w_in,w_out)->bf16 ; gemm_bt(x,w_in)->P[4096][6144] ;
//           flash attn -> O[4096][2048] ; gemm_bt(O,w_out)->out fp32.
// MFMA 16x16x32 bf16. Verified layouts (learn_hip m89/m120):
//   A-frag: m=lane&15, k=quad*8+j (8 contiguous bf16 = 16B load)
//   B-frag: n=lane&15, k=quad*8+j (from B^T i.e. [N][K] storage)
//   C/D:    col=lane&15, row=quad*4+reg

typedef short bf16x8 __attribute__((ext_vector_type(8)));
typedef float f32x4 __attribute__((ext_vector_type(4)));

#define NEG_BIG -30000.0f

__device__ __forceinline__ short f2bf(float f) {
    union { float f; unsigned u; } v; v.f = f;
    unsigned r = v.u + 0x7fffu + ((v.u >> 16) & 1u);  // RNE
    return (short)(r >> 16);
}

// fp32 -> bf16 elementwise (n divisible by 4)
__global__ __launch_bounds__(256) void cvt_f32_bf16(const float* __restrict__ src,
                                                    short* __restrict__ dst, int n) {
    int i = (blockIdx.x * blockDim.x + threadIdx.x) * 4;
    if (i < n) {
        float4 v = *(const float4*)(src + i);
        short4 o;
        o.x = f2bf(v.x); o.y = f2bf(v.y); o.z = f2bf(v.z); o.w = f2bf(v.w);
        *(short4*)(dst + i) = o;
    }
}

// C[M][N] = A[M][K] * B[N][K]^T   (bf16 in, fp32 acc, out bf16 or fp32)
// block = 256 threads = 4 waves; block tile 64x64; wave tile 32x32 (2x2 MFMA)
template <bool F32OUT>
__global__ __launch_bounds__(256) void gemm_bt(const short* __restrict__ A,
                                               const short* __restrict__ Bm,
                                               void* __restrict__ Cv,
                                               int N, int K) {
    const int lane = threadIdx.x & 63;
    const int wave = threadIdx.x >> 6;
    const int l15 = lane & 15, quad = lane >> 4;
    const int m0 = blockIdx.y * 64 + (wave >> 1) * 32;
    const int n0 = blockIdx.x * 64 + (wave & 1) * 32;
    f32x4 acc[2][2] = {};
    const short* Ap = A + (size_t)(m0 + l15) * K + quad * 8;
    const short* Bp = Bm + (size_t)(n0 + l15) * K + quad * 8;
    const size_t rs16 = (size_t)16 * K;
    for (int k0 = 0; k0 < K; k0 += 32) {
        bf16x8 a0 = *(const bf16x8*)(Ap + k0);
        bf16x8 a1 = *(const bf16x8*)(Ap + rs16 + k0);
        bf16x8 b0 = *(const bf16x8*)(Bp + k0);
        bf16x8 b1 = *(const bf16x8*)(Bp + rs16 + k0);
        acc[0][0] = __builtin_amdgcn_mfma_f32_16x16x32_bf16(a0, b0, acc[0][0], 0, 0, 0);
        acc[0][1] = __builtin_amdgcn_mfma_f32_16x16x32_bf16(a0, b1, acc[0][1], 0, 0, 0);
        acc[1][0] = __builtin_amdgcn_mfma_f32_16x16x32_bf16(a1, b0, acc[1][0], 0, 0, 0);
        acc[1][1] = __builtin_amdgcn_mfma_f32_16x16x32_bf16(a1, b1, acc[1][1], 0, 0, 0);
    }
    #pragma unroll
    for (int i = 0; i < 2; i++)
        #pragma unroll
        for (int j = 0; j < 2; j++)
            #pragma unroll
            for (int r = 0; r < 4; r++) {
                int row = m0 + i * 16 + quad * 4 + r;
                int col = n0 + j * 16 + l15;
                if (F32OUT)
                    ((float*)Cv)[(size_t)row * N + col] = acc[i][j][r];
                else
                    ((short*)Cv)[(size_t)row * N + col] = f2bf(acc[i][j][r]);
            }
}

// Flash attention, causal. P rows = b*2048+s, cols: head h at h*384 (+0 q, +128 k, +256 v).
// grid = (32 q-tiles, 16 heads, 2 batch); 4 waves/block; wave owns 16 q-rows.
__global__ __launch_bounds__(256) void attn_kernel(const short* __restrict__ P,
                                                   short* __restrict__ O) {
    constexpr int S = 2048, ROWW = 6144, HD = 2048;
    const int qt = blockIdx.x, h = blockIdx.y, b = blockIdx.z;
    const int wave = threadIdx.x >> 6, lane = threadIdx.x & 63;
    const int l15 = lane & 15, quad = lane >> 4;
    const int qBase = qt * 64;
    const int qRow = qBase + wave * 16;
    const short* Pb = P + (size_t)b * S * ROWW;
    const short* Qp = Pb + h * 384;
    const short* Kp = Qp + 128;
    const short* Vp = Qp + 256;

    // Q tile (16 x 128) as 4 A-frags, reused across all k-tiles
    bf16x8 qf[4];
    #pragma unroll
    for (int f = 0; f < 4; f++)
        qf[f] = *(const bf16x8*)(Qp + (size_t)(qRow + l15) * ROWW + f * 32 + quad * 8);

    f32x4 accO[8] = {};                 // O tile 16 x 128 in C-layout (8 col-tiles)
    float m_i[4], l_i[4];
    #pragma unroll
    for (int r = 0; r < 4; r++) { m_i[r] = NEG_BIG; l_i[r] = 0.f; }

    __shared__ short pTile[4][16 * 32]; // per-wave P round-trip (C-layout -> A-layout)
    short* myP = pTile[wave];

    const int kTiles = qt * 2 + 2;      // cover keys 0 .. qBase+63 (uniform per block)
    const float scale = 0.08838834764831845f; // 1/sqrt(128)

    for (int kt = 0; kt < kTiles; kt++) {
        const int kBase = kt * 32;
        // S-tile (16 q x 32 k) via two 16x16 C-frags
        f32x4 sc[2] = {};
        #pragma unroll
        for (int half = 0; half < 2; half++) {
            const short* kp = Kp + (size_t)(kBase + half * 16 + l15) * ROWW + quad * 8;
            #pragma unroll
            for (int f = 0; f < 4; f++) {
                bf16x8 kf = *(const bf16x8*)(kp + f * 32);
                sc[half] = __builtin_amdgcn_mfma_f32_16x16x32_bf16(qf[f], kf, sc[half], 0, 0, 0);
            }
        }
        // scale + causal mask (element: q = qRow+quad*4+r, key = kBase+half*16+l15)
        #pragma unroll
        for (int half = 0; half < 2; half++) {
            int key = kBase + half * 16 + l15;
            #pragma unroll
            for (int r = 0; r < 4; r++) {
                int q = qRow + quad * 4 + r;
                float v = sc[half][r] * scale;
                sc[half][r] = (key <= q) ? v : NEG_BIG;
            }
        }
        // row max across 32 cols: lane-local then 16-lane butterfly
        float rm[4];
        #pragma unroll
        for (int r = 0; r < 4; r++) rm[r] = fmaxf(sc[0][r], sc[1][r]);
        #pragma unroll
        for (int off = 1; off < 16; off <<= 1)
            #pragma unroll
            for (int r = 0; r < 4; r++) rm[r] = fmaxf(rm[r], __shfl_xor(rm[r], off, 64));

        float alpha[4], nm[4];
        #pragma unroll
        for (int r = 0; r < 4; r++) {
            nm[r] = fmaxf(m_i[r], rm[r]);
            alpha[r] = expf(m_i[r] - nm[r]);
            m_i[r] = nm[r];
        }
        float ps[4];
        #pragma unroll
        for (int r = 0; r < 4; r++) {
            float p0 = expf(sc[0][r] - nm[r]);
            float p1 = expf(sc[1][r] - nm[r]);
            sc[0][r] = p0; sc[1][r] = p1;
            ps[r] = p0 + p1;
        }
        #pragma unroll
        for (int off = 1; off < 16; off <<= 1)
            #pragma unroll
            for (int r = 0; r < 4; r++) ps[r] += __shfl_xor(ps[r], off, 64);
        #pragma unroll
        for (int r = 0; r < 4; r++) l_i[r] = alpha[r] * l_i[r] + ps[r];
        // rescale running O
        #pragma unroll
        for (int t = 0; t < 8; t++)
            #pragma unroll
            for (int r = 0; r < 4; r++) accO[t][r] *= alpha[r];
        // P: C-layout -> [m][k] in LDS, barrier-fenced both sides
        #pragma unroll
        for (int half = 0; half < 2; half++)
            #pragma unroll
            for (int r = 0; r < 4; r++)
                myP[(quad * 4 + r) * 32 + half * 16 + l15] = f2bf(sc[half][r]);
        __syncthreads();
        bf16x8 pf = *(const bf16x8*)(myP + l15 * 32 + quad * 8);
        __syncthreads();
        // PV: V B-frags via scalar loads (k-strided); O += P(16x32) * V(32x128)
        const short* vp = Vp + (size_t)(kBase + quad * 8) * ROWW + l15;
        #pragma unroll
        for (int t = 0; t < 8; t++) {
            bf16x8 vf;
            #pragma unroll
            for (int j = 0; j < 8; j++) vf[j] = vp[(size_t)j * ROWW + t * 16];
            accO[t] = __builtin_amdgcn_mfma_f32_16x16x32_bf16(pf, vf, accO[t], 0, 0, 0);
        }
    }
    float inv[4];
    #pragma unroll
    for (int r = 0; r < 4; r++) inv[r] = 1.0f / l_i[r];
    #pragma unroll
    for (int t = 0; t < 8; t++)
        #pragma unroll
        for (int r = 0; r < 4; r++) {
            int row = b * S + qRow + quad * 4 + r;
            int col = h * 128 + t * 16 + l15;
            O[(size_t)row * HD + col] = f2bf(accO[t][r] * inv[r]);
        }
}

extern "C" void kernel_launch(void* const* d_in, const int* in_sizes, int n_in,
                              void* d_out, int out_size, void* d_ws, size_t ws_size,
                              hipStream_t stream) {
    const float* x     = (const float*)d_in[0];  // [2,2048,2048] fp32
    const float* w_in  = (const float*)d_in[1];  // [6144,2048]  fp32
    const float* w_out = (const float*)d_in[2];  // [2048,2048]  fp32
    float* out = (float*)d_out;                  // [2,2048,2048] fp32

    // Workspace layout (96 MiB total):
    //   P      [4096*6144] bf16  50.3 MB
    //   xO     [8388608]   bf16  16.8 MB  (x_bf16 during GEMM1; O after attn)
    //   w_in_b [6144*2048] bf16  25.2 MB
    //   w_out_b[2048*2048] bf16   8.4 MB
    short* Pbuf   = (short*)d_ws;
    short* xObuf  = Pbuf  + (size_t)4096 * 6144;
    short* winb   = xObuf + (size_t)8388608;
    short* woutb  = winb  + (size_t)6144 * 2048;

    dim3 blk(256, 1, 1);
    const int nx = 2 * 2048 * 2048, nwi = 6144 * 2048, nwo = 2048 * 2048;
    hipLaunchKernelGGL(cvt_f32_bf16, dim3(nx / 1024), blk, 0, stream, x, xObuf, nx);
    hipLaunchKernelGGL(cvt_f32_bf16, dim3(nwi / 1024), blk, 0, stream, w_in, winb, nwi);
    hipLaunchKernelGGL(cvt_f32_bf16, dim3(nwo / 1024), blk, 0, stream, w_out, woutb, nwo);
    // GEMM1: P = x @ w_in^T   (M=4096, N=6144, K=2048), bf16 out
    hipLaunchKernelGGL((gemm_bt<false>), dim3(96, 64, 1), blk, 0, stream, xObuf, winb, (void*)Pbuf, 6144, 2048);
    // Flash attention (x_bf16 dead now; O overwrites it)
    hipLaunchKernelGGL(attn_kernel, dim3(32, 16, 2), blk, 0, stream, Pbuf, xObuf);
    // GEMM2: out = O @ w_out^T (M=4096, N=2048, K=2048), fp32 out
    hipLaunchKernelGGL((gemm_bt<true>), dim3(32, 64, 1), blk, 0, stream, xObuf, woutb, (void*)out, 2048, 2048);
}

// Round 4
// 755.358 us; speedup vs baseline: 1.9554x; 1.9554x over previous
//
#include <hip/hip_runtime.h>
#include <hip/hip_bf16.h>
#include <math.h>

// Problem: Attention_58102317580396
// B=2, S=2048, D=2048, H=16, DH=128. Inputs/outputs FP32; internal bf16 MFMA.
// Pipeline: cvt(x,w_in,w_out)->bf16 ; gemm_bt(x,w_in)->P[4096][6144] ;
//           flash attn -> O[4096][2048] ; gemm_bt(O,w_out)->out fp32.
// R4: gemm_bt rewritten to m97-ladder structure: 128x128 block tile, BK=32,
// global_load_lds width=16 staging, 4 waves x (4x4) 16x16x32 MFMA accs,
// 2-barrier K-loop. (Prev: direct global fragment loads, MfmaUtil 5.9%.)
// Verified layouts (learn_hip m89/m120):
//   A-frag: m=lane&15, k=quad*8+j ; B-frag: n=lane&15, k=quad*8+j (B^T [N][K])
//   C/D:    col=lane&15, row=quad*4+reg

typedef short bf16x8 __attribute__((ext_vector_type(8)));
typedef float f32x4 __attribute__((ext_vector_type(4)));

#define NEG_BIG -30000.0f

__device__ __forceinline__ short f2bf(float f) {
    union { float f; unsigned u; } v; v.f = f;
    unsigned r = v.u + 0x7fffu + ((v.u >> 16) & 1u);  // RNE
    return (short)(r >> 16);
}

#define GLDS16(g, l) \
    __builtin_amdgcn_global_load_lds((const __attribute__((address_space(1))) void*)(g), \
                                     (__attribute__((address_space(3))) void*)(l), 16, 0, 0)

// fp32 -> bf16 elementwise (n divisible by 1024)
__global__ __launch_bounds__(256) void cvt_f32_bf16(const float* __restrict__ src,
                                                    short* __restrict__ dst, int n) {
    int i = (blockIdx.x * blockDim.x + threadIdx.x) * 4;
    if (i < n) {
        float4 v = *(const float4*)(src + i);
        short4 o;
        o.x = f2bf(v.x); o.y = f2bf(v.y); o.z = f2bf(v.z); o.w = f2bf(v.w);
        *(short4*)(dst + i) = o;
    }
}

// C[M][N] = A[M][K] * B[N][K]^T  (bf16 in, fp32 acc, bf16 or fp32 out)
// m97 structure: block 256 = 4 waves; block tile 128x128; wave tile 64x64.
// LDS: sA[128][32], sB[128][32] bf16 (16 KB). K assumed %32==0, M%128, N%128.
template <bool F32OUT>
__global__ __launch_bounds__(256) void gemm_bt(const short* __restrict__ A,
                                               const short* __restrict__ Bm,
                                               void* __restrict__ Cv,
                                               int N, int K) {
    __shared__ short sA[128 * 32];
    __shared__ short sB[128 * 32];
    const int lane = threadIdx.x & 63;
    const int w = threadIdx.x >> 6;
    const int l15 = lane & 15, quad = lane >> 4;
    const int bm0 = blockIdx.y * 128, bn0 = blockIdx.x * 128;

    // Staging: tile = 512 chunks of 8 bf16; thread t owns chunks (w*64+lane)
    // and +256. chunk c -> row c>>2, kcol (c&3)*8. LDS dst is wave-uniform
    // base + lane*16 (global_load_lds constraint) == chunk-ordered layout.
    const int c1 = w * 64 + lane;
    const short* gA = A + (size_t)(bm0 + (c1 >> 2)) * K + (c1 & 3) * 8;
    const short* gB = Bm + (size_t)(bn0 + (c1 >> 2)) * K + (c1 & 3) * 8;
    const size_t half = (size_t)64 * K;  // chunk c+256 -> row +64
    short* lA1 = sA + w * 512;           // 64 chunks * 8 shorts per wave
    short* lA2 = sA + 2048 + w * 512;
    short* lB1 = sB + w * 512;
    short* lB2 = sB + 2048 + w * 512;

    // Compute-side fragment pointers: wave (wm,wn) in 2x2 grid of 64x64 tiles
    const int wm = (w >> 1) * 64, wn = (w & 1) * 64;
    const short* pa = sA + (wm + l15) * 32 + quad * 8;
    const short* pb = sB + (wn + l15) * 32 + quad * 8;

    f32x4 acc[4][4] = {};
    for (int k0 = 0; k0 < K; k0 += 32) {
        GLDS16(gA + k0, lA1);
        GLDS16(gA + half + k0, lA2);
        GLDS16(gB + k0, lB1);
        GLDS16(gB + half + k0, lB2);
        __syncthreads();  // drain loads (vmcnt) before fragment reads
        bf16x8 af[4], bf[4];
        #pragma unroll
        for (int mt = 0; mt < 4; mt++) af[mt] = *(const bf16x8*)(pa + mt * 512);
        #pragma unroll
        for (int nt = 0; nt < 4; nt++) bf[nt] = *(const bf16x8*)(pb + nt * 512);
        #pragma unroll
        for (int mt = 0; mt < 4; mt++)
            #pragma unroll
            for (int nt = 0; nt < 4; nt++)
                acc[mt][nt] = __builtin_amdgcn_mfma_f32_16x16x32_bf16(af[mt], bf[nt], acc[mt][nt], 0, 0, 0);
        __syncthreads();  // LDS consumed; next iter may overwrite
    }
    #pragma unroll
    for (int mt = 0; mt < 4; mt++)
        #pragma unroll
        for (int nt = 0; nt < 4; nt++)
            #pragma unroll
            for (int r = 0; r < 4; r++) {
                int row = bm0 + wm + mt * 16 + quad * 4 + r;
                int col = bn0 + wn + nt * 16 + l15;
                if (F32OUT)
                    ((float*)Cv)[(size_t)row * N + col] = acc[mt][nt][r];
                else
                    ((short*)Cv)[(size_t)row * N + col] = f2bf(acc[mt][nt][r]);
            }
}

// Flash attention, causal. P rows = b*2048+s, cols: head h at h*384 (+0 q, +128 k, +256 v).
// grid = (32 q-tiles, 16 heads, 2 batch); 4 waves/block; wave owns 16 q-rows.
__global__ __launch_bounds__(256) void attn_kernel(const short* __restrict__ P,
                                                   short* __restrict__ O) {
    constexpr int S = 2048, ROWW = 6144, HD = 2048;
    const int qt = blockIdx.x, h = blockIdx.y, b = blockIdx.z;
    const int wave = threadIdx.x >> 6, lane = threadIdx.x & 63;
    const int l15 = lane & 15, quad = lane >> 4;
    const int qBase = qt * 64;
    const int qRow = qBase + wave * 16;
    const short* Pb = P + (size_t)b * S * ROWW;
    const short* Qp = Pb + h * 384;
    const short* Kp = Qp + 128;
    const short* Vp = Qp + 256;

    bf16x8 qf[4];
    #pragma unroll
    for (int f = 0; f < 4; f++)
        qf[f] = *(const bf16x8*)(Qp + (size_t)(qRow + l15) * ROWW + f * 32 + quad * 8);

    f32x4 accO[8] = {};
    float m_i[4], l_i[4];
    #pragma unroll
    for (int r = 0; r < 4; r++) { m_i[r] = NEG_BIG; l_i[r] = 0.f; }

    __shared__ short pTile[4][16 * 32];
    short* myP = pTile[wave];

    const int kTiles = qt * 2 + 2;
    const float scale = 0.08838834764831845f; // 1/sqrt(128)

    for (int kt = 0; kt < kTiles; kt++) {
        const int kBase = kt * 32;
        f32x4 sc[2] = {};
        #pragma unroll
        for (int half = 0; half < 2; half++) {
            const short* kp = Kp + (size_t)(kBase + half * 16 + l15) * ROWW + quad * 8;
            #pragma unroll
            for (int f = 0; f < 4; f++) {
                bf16x8 kf = *(const bf16x8*)(kp + f * 32);
                sc[half] = __builtin_amdgcn_mfma_f32_16x16x32_bf16(qf[f], kf, sc[half], 0, 0, 0);
            }
        }
        #pragma unroll
        for (int half = 0; half < 2; half++) {
            int key = kBase + half * 16 + l15;
            #pragma unroll
            for (int r = 0; r < 4; r++) {
                int q = qRow + quad * 4 + r;
                float v = sc[half][r] * scale;
                sc[half][r] = (key <= q) ? v : NEG_BIG;
            }
        }
        float rm[4];
        #pragma unroll
        for (int r = 0; r < 4; r++) rm[r] = fmaxf(sc[0][r], sc[1][r]);
        #pragma unroll
        for (int off = 1; off < 16; off <<= 1)
            #pragma unroll
            for (int r = 0; r < 4; r++) rm[r] = fmaxf(rm[r], __shfl_xor(rm[r], off, 64));

        float alpha[4], nm[4];
        #pragma unroll
        for (int r = 0; r < 4; r++) {
            nm[r] = fmaxf(m_i[r], rm[r]);
            alpha[r] = expf(m_i[r] - nm[r]);
            m_i[r] = nm[r];
        }
        float ps[4];
        #pragma unroll
        for (int r = 0; r < 4; r++) {
            float p0 = expf(sc[0][r] - nm[r]);
            float p1 = expf(sc[1][r] - nm[r]);
            sc[0][r] = p0; sc[1][r] = p1;
            ps[r] = p0 + p1;
        }
        #pragma unroll
        for (int off = 1; off < 16; off <<= 1)
            #pragma unroll
            for (int r = 0; r < 4; r++) ps[r] += __shfl_xor(ps[r], off, 64);
        #pragma unroll
        for (int r = 0; r < 4; r++) l_i[r] = alpha[r] * l_i[r] + ps[r];
        #pragma unroll
        for (int t = 0; t < 8; t++)
            #pragma unroll
            for (int r = 0; r < 4; r++) accO[t][r] *= alpha[r];
        #pragma unroll
        for (int half = 0; half < 2; half++)
            #pragma unroll
            for (int r = 0; r < 4; r++)
                myP[(quad * 4 + r) * 32 + half * 16 + l15] = f2bf(sc[half][r]);
        __syncthreads();
        bf16x8 pf = *(const bf16x8*)(myP + l15 * 32 + quad * 8);
        __syncthreads();
        const short* vp = Vp + (size_t)(kBase + quad * 8) * ROWW + l15;
        #pragma unroll
        for (int t = 0; t < 8; t++) {
            bf16x8 vf;
            #pragma unroll
            for (int j = 0; j < 8; j++) vf[j] = vp[(size_t)j * ROWW + t * 16];
            accO[t] = __builtin_amdgcn_mfma_f32_16x16x32_bf16(pf, vf, accO[t], 0, 0, 0);
        }
    }
    float inv[4];
    #pragma unroll
    for (int r = 0; r < 4; r++) inv[r] = 1.0f / l_i[r];
    #pragma unroll
    for (int t = 0; t < 8; t++)
        #pragma unroll
        for (int r = 0; r < 4; r++) {
            int row = b * S + qRow + quad * 4 + r;
            int col = h * 128 + t * 16 + l15;
            O[(size_t)row * HD + col] = f2bf(accO[t][r] * inv[r]);
        }
}

extern "C" void kernel_launch(void* const* d_in, const int* in_sizes, int n_in,
                              void* d_out, int out_size, void* d_ws, size_t ws_size,
                              hipStream_t stream) {
    const float* x     = (const float*)d_in[0];  // [2,2048,2048] fp32
    const float* w_in  = (const float*)d_in[1];  // [6144,2048]  fp32
    const float* w_out = (const float*)d_in[2];  // [2048,2048]  fp32
    float* out = (float*)d_out;                  // [2,2048,2048] fp32

    // Workspace (96 MiB): P[4096*6144] bf16 | xO[8388608] bf16 (x_bf16 then O)
    //                     | w_in_b[6144*2048] bf16 | w_out_b[2048*2048] bf16
    short* Pbuf   = (short*)d_ws;
    short* xObuf  = Pbuf  + (size_t)4096 * 6144;
    short* winb   = xObuf + (size_t)8388608;
    short* woutb  = winb  + (size_t)6144 * 2048;

    dim3 blk(256, 1, 1);
    const int nx = 2 * 2048 * 2048, nwi = 6144 * 2048, nwo = 2048 * 2048;
    hipLaunchKernelGGL(cvt_f32_bf16, dim3(nx / 1024), blk, 0, stream, x, xObuf, nx);
    hipLaunchKernelGGL(cvt_f32_bf16, dim3(nwi / 1024), blk, 0, stream, w_in, winb, nwi);
    hipLaunchKernelGGL(cvt_f32_bf16, dim3(nwo / 1024), blk, 0, stream, w_out, woutb, nwo);
    // GEMM1: P = x @ w_in^T   (M=4096, N=6144, K=2048), bf16 out
    hipLaunchKernelGGL((gemm_bt<false>), dim3(48, 32, 1), blk, 0, stream, xObuf, winb, (void*)Pbuf, 6144, 2048);
    // Flash attention (x_bf16 dead now; O overwrites it)
    hipLaunchKernelGGL(attn_kernel, dim3(32, 16, 2), blk, 0, stream, Pbuf, xObuf);
    // GEMM2: out = O @ w_out^T (M=4096, N=2048, K=2048), fp32 out
    hipLaunchKernelGGL((gemm_bt<true>), dim3(16, 32, 1), blk, 0, stream, xObuf, woutb, (void*)out, 2048, 2048);
}

// Round 5
// 681.441 us; speedup vs baseline: 2.1675x; 1.1085x over previous
//
#include <hip/hip_runtime.h>
#include <hip/hip_bf16.h>
#include <math.h>

// Problem: Attention_58102317580396
// B=2, S=2048, D=2048, H=16, DH=128. Inputs/outputs FP32; internal bf16 MFMA.
// Pipeline: cvt(x,w_in,w_out)->bf16 ; gemm_bt(x,w_in)->P[4096][6144] ;
//           flash attn -> O[4096][2048] ; gemm_bt(O,w_out)->out fp32.
// R5: attn_kernel restaged — K-tile via global_load_lds(16) into LDS (block-
// shared), V-tile transposed into LDS (pitch 40 shorts, 16B-aligned rows);
// PV V-frags become ds_read_b128 (was 64 scalar global loads/wave/tile,
// MfmaUtil 3.1%, latency-bound).
// Verified layouts (learn_hip m89/m120):
//   A-frag: m=lane&15, k=quad*8+j ; B-frag: n=lane&15, k=quad*8+j (B^T [N][K])
//   C/D:    col=lane&15, row=quad*4+reg

typedef short bf16x8 __attribute__((ext_vector_type(8)));
typedef float f32x4 __attribute__((ext_vector_type(4)));

#define NEG_BIG -30000.0f

__device__ __forceinline__ short f2bf(float f) {
    union { float f; unsigned u; } v; v.f = f;
    unsigned r = v.u + 0x7fffu + ((v.u >> 16) & 1u);  // RNE
    return (short)(r >> 16);
}

#define GLDS16(g, l) \
    __builtin_amdgcn_global_load_lds((const __attribute__((address_space(1))) void*)(g), \
                                     (__attribute__((address_space(3))) void*)(l), 16, 0, 0)

// fp32 -> bf16 elementwise (n divisible by 1024)
__global__ __launch_bounds__(256) void cvt_f32_bf16(const float* __restrict__ src,
                                                    short* __restrict__ dst, int n) {
    int i = (blockIdx.x * blockDim.x + threadIdx.x) * 4;
    if (i < n) {
        float4 v = *(const float4*)(src + i);
        short4 o;
        o.x = f2bf(v.x); o.y = f2bf(v.y); o.z = f2bf(v.z); o.w = f2bf(v.w);
        *(short4*)(dst + i) = o;
    }
}

// C[M][N] = A[M][K] * B[N][K]^T  (bf16 in, fp32 acc, bf16 or fp32 out)
// m97 structure: block 256 = 4 waves; block tile 128x128; wave tile 64x64.
template <bool F32OUT>
__global__ __launch_bounds__(256) void gemm_bt(const short* __restrict__ A,
                                               const short* __restrict__ Bm,
                                               void* __restrict__ Cv,
                                               int N, int K) {
    __shared__ short sA[128 * 32];
    __shared__ short sB[128 * 32];
    const int lane = threadIdx.x & 63;
    const int w = threadIdx.x >> 6;
    const int l15 = lane & 15, quad = lane >> 4;
    const int bm0 = blockIdx.y * 128, bn0 = blockIdx.x * 128;

    const int c1 = w * 64 + lane;
    const short* gA = A + (size_t)(bm0 + (c1 >> 2)) * K + (c1 & 3) * 8;
    const short* gB = Bm + (size_t)(bn0 + (c1 >> 2)) * K + (c1 & 3) * 8;
    const size_t half = (size_t)64 * K;
    short* lA1 = sA + w * 512;
    short* lA2 = sA + 2048 + w * 512;
    short* lB1 = sB + w * 512;
    short* lB2 = sB + 2048 + w * 512;

    const int wm = (w >> 1) * 64, wn = (w & 1) * 64;
    const short* pa = sA + (wm + l15) * 32 + quad * 8;
    const short* pb = sB + (wn + l15) * 32 + quad * 8;

    f32x4 acc[4][4] = {};
    for (int k0 = 0; k0 < K; k0 += 32) {
        GLDS16(gA + k0, lA1);
        GLDS16(gA + half + k0, lA2);
        GLDS16(gB + k0, lB1);
        GLDS16(gB + half + k0, lB2);
        __syncthreads();
        bf16x8 af[4], bf[4];
        #pragma unroll
        for (int mt = 0; mt < 4; mt++) af[mt] = *(const bf16x8*)(pa + mt * 512);
        #pragma unroll
        for (int nt = 0; nt < 4; nt++) bf[nt] = *(const bf16x8*)(pb + nt * 512);
        #pragma unroll
        for (int mt = 0; mt < 4; mt++)
            #pragma unroll
            for (int nt = 0; nt < 4; nt++)
                acc[mt][nt] = __builtin_amdgcn_mfma_f32_16x16x32_bf16(af[mt], bf[nt], acc[mt][nt], 0, 0, 0);
        __syncthreads();
    }
    #pragma unroll
    for (int mt = 0; mt < 4; mt++)
        #pragma unroll
        for (int nt = 0; nt < 4; nt++)
            #pragma unroll
            for (int r = 0; r < 4; r++) {
                int row = bm0 + wm + mt * 16 + quad * 4 + r;
                int col = bn0 + wn + nt * 16 + l15;
                if (F32OUT)
                    ((float*)Cv)[(size_t)row * N + col] = acc[mt][nt][r];
                else
                    ((short*)Cv)[(size_t)row * N + col] = f2bf(acc[mt][nt][r]);
            }
}

// Flash attention, causal. P rows = b*2048+s, cols: head h at h*384 (+0 q, +128 k, +256 v).
// grid = (32 q-tiles, 16 heads, 2 batch); 4 waves/block; wave owns 16 q-rows.
// K/V tiles staged in LDS per block: sK[32][128] natural, sVt transposed
// [128 d][32 key] pitch 40 shorts (80 B rows: 16B-aligned, odd-dword stride).
#define VP 40
__global__ __launch_bounds__(256) void attn_kernel(const short* __restrict__ P,
                                                   short* __restrict__ O) {
    constexpr int S = 2048, ROWW = 6144, HD = 2048;
    const int qt = blockIdx.x, h = blockIdx.y, b = blockIdx.z;
    const int wave = threadIdx.x >> 6, lane = threadIdx.x & 63;
    const int l15 = lane & 15, quad = lane >> 4;
    const int qBase = qt * 64;
    const int qRow = qBase + wave * 16;
    const short* Pb = P + (size_t)b * S * ROWW;
    const short* Qp = Pb + h * 384;
    const short* Kp = Qp + 128;
    const short* Vp = Qp + 256;

    __shared__ short sK[32 * 128];      // 8 KB, rows = key, natural layout
    __shared__ short sVt[128 * VP];     // 10 KB, rows = d, transposed
    __shared__ short pTile[4][16 * 32]; // 4 KB, per-wave P roundtrip

    bf16x8 qf[4];
    #pragma unroll
    for (int f = 0; f < 4; f++)
        qf[f] = *(const bf16x8*)(Qp + (size_t)(qRow + l15) * ROWW + f * 32 + quad * 8);

    f32x4 accO[8] = {};
    float m_i[4], l_i[4];
    #pragma unroll
    for (int r = 0; r < 4; r++) { m_i[r] = NEG_BIG; l_i[r] = 0.f; }
    short* myP = pTile[wave];

    // K staging: chunk c = wave*64+lane -> key = wave*4 + (lane>>4), kd = (lane&15)*8;
    // second batch key += 16. LDS dst wave-uniform + lane*16 == natural row-major.
    const short* gK = Kp + (size_t)(wave * 4 + (lane >> 4)) * ROWW + (lane & 15) * 8;
    short* lK1 = sK + wave * 512;
    short* lK2 = sK + 2048 + wave * 512;
    // V staging: thread t owns chunks t, t+256: chunk c -> key = c&31, d0 = (c>>5)*8
    const int tid = threadIdx.x;
    const int vKey = tid & 31;
    const int vD0 = (tid >> 5) * 8;          // 0..56 ; +64 for second chunk
    const short* gV = Vp + (size_t)vKey * ROWW + vD0;

    const int kTiles = qt * 2 + 2;
    const float scale = 0.08838834764831845f; // 1/sqrt(128)

    for (int kt = 0; kt < kTiles; kt++) {
        const size_t kOff = (size_t)(kt * 32) * ROWW;
        // stage K (async to LDS) and V (regs -> transposed LDS writes)
        GLDS16(gK + kOff, lK1);
        GLDS16(gK + kOff + (size_t)16 * ROWW, lK2);
        bf16x8 v0 = *(const bf16x8*)(gV + kOff);
        bf16x8 v1 = *(const bf16x8*)(gV + kOff + 64);
        #pragma unroll
        for (int j = 0; j < 8; j++) {
            sVt[(vD0 + j) * VP + vKey] = v0[j];
            sVt[(vD0 + 64 + j) * VP + vKey] = v1[j];
        }
        __syncthreads();  // staging visible to all waves

        // QK^T: S-tile (16 q x 32 k), K B-frags from sK
        f32x4 sc[2] = {};
        #pragma unroll
        for (int half = 0; half < 2; half++) {
            const short* kp = sK + (half * 16 + l15) * 128 + quad * 8;
            #pragma unroll
            for (int f = 0; f < 4; f++) {
                bf16x8 kf = *(const bf16x8*)(kp + f * 32);
                sc[half] = __builtin_amdgcn_mfma_f32_16x16x32_bf16(qf[f], kf, sc[half], 0, 0, 0);
            }
        }
        // scale + causal mask
        #pragma unroll
        for (int half = 0; half < 2; half++) {
            int key = kt * 32 + half * 16 + l15;
            #pragma unroll
            for (int r = 0; r < 4; r++) {
                int q = qRow + quad * 4 + r;
                float v = sc[half][r] * scale;
                sc[half][r] = (key <= q) ? v : NEG_BIG;
            }
        }
        // online softmax (rows live within quad-groups; 16-lane butterfly)
        float rm[4];
        #pragma unroll
        for (int r = 0; r < 4; r++) rm[r] = fmaxf(sc[0][r], sc[1][r]);
        #pragma unroll
        for (int off = 1; off < 16; off <<= 1)
            #pragma unroll
            for (int r = 0; r < 4; r++) rm[r] = fmaxf(rm[r], __shfl_xor(rm[r], off, 64));
        float alpha[4], nm[4];
        #pragma unroll
        for (int r = 0; r < 4; r++) {
            nm[r] = fmaxf(m_i[r], rm[r]);
            alpha[r] = expf(m_i[r] - nm[r]);
            m_i[r] = nm[r];
        }
        float ps[4];
        #pragma unroll
        for (int r = 0; r < 4; r++) {
            float p0 = expf(sc[0][r] - nm[r]);
            float p1 = expf(sc[1][r] - nm[r]);
            sc[0][r] = p0; sc[1][r] = p1;
            ps[r] = p0 + p1;
        }
        #pragma unroll
        for (int off = 1; off < 16; off <<= 1)
            #pragma unroll
            for (int r = 0; r < 4; r++) ps[r] += __shfl_xor(ps[r], off, 64);
        #pragma unroll
        for (int r = 0; r < 4; r++) l_i[r] = alpha[r] * l_i[r] + ps[r];
        #pragma unroll
        for (int t = 0; t < 8; t++)
            #pragma unroll
            for (int r = 0; r < 4; r++) accO[t][r] *= alpha[r];
        // P: C-layout -> A-layout via per-wave LDS roundtrip
        #pragma unroll
        for (int half = 0; half < 2; half++)
            #pragma unroll
            for (int r = 0; r < 4; r++)
                myP[(quad * 4 + r) * 32 + half * 16 + l15] = f2bf(sc[half][r]);
        __syncthreads();  // orders P writes before read; also fences QK's sK reads
        bf16x8 pf = *(const bf16x8*)(myP + l15 * 32 + quad * 8);
        // PV: V B-frags are contiguous ds_read_b128 from sVt
        #pragma unroll
        for (int t = 0; t < 8; t++) {
            bf16x8 vf = *(const bf16x8*)(sVt + (t * 16 + l15) * VP + quad * 8);
            accO[t] = __builtin_amdgcn_mfma_f32_16x16x32_bf16(pf, vf, accO[t], 0, 0, 0);
        }
        __syncthreads();  // all LDS reads done before next iter's staging
    }
    float inv[4];
    #pragma unroll
    for (int r = 0; r < 4; r++) inv[r] = 1.0f / l_i[r];
    #pragma unroll
    for (int t = 0; t < 8; t++)
        #pragma unroll
        for (int r = 0; r < 4; r++) {
            int row = b * S + qRow + quad * 4 + r;
            int col = h * 128 + t * 16 + l15;
            O[(size_t)row * HD + col] = f2bf(accO[t][r] * inv[r]);
        }
}

extern "C" void kernel_launch(void* const* d_in, const int* in_sizes, int n_in,
                              void* d_out, int out_size, void* d_ws, size_t ws_size,
                              hipStream_t stream) {
    const float* x     = (const float*)d_in[0];  // [2,2048,2048] fp32
    const float* w_in  = (const float*)d_in[1];  // [6144,2048]  fp32
    const float* w_out = (const float*)d_in[2];  // [2048,2048]  fp32
    float* out = (float*)d_out;                  // [2,2048,2048] fp32

    // Workspace (96 MiB): P[4096*6144] bf16 | xO[8388608] bf16 (x_bf16 then O)
    //                     | w_in_b[6144*2048] bf16 | w_out_b[2048*2048] bf16
    short* Pbuf   = (short*)d_ws;
    short* xObuf  = Pbuf  + (size_t)4096 * 6144;
    short* winb   = xObuf + (size_t)8388608;
    short* woutb  = winb  + (size_t)6144 * 2048;

    dim3 blk(256, 1, 1);
    const int nx = 2 * 2048 * 2048, nwi = 6144 * 2048, nwo = 2048 * 2048;
    hipLaunchKernelGGL(cvt_f32_bf16, dim3(nx / 1024), blk, 0, stream, x, xObuf, nx);
    hipLaunchKernelGGL(cvt_f32_bf16, dim3(nwi / 1024), blk, 0, stream, w_in, winb, nwi);
    hipLaunchKernelGGL(cvt_f32_bf16, dim3(nwo / 1024), blk, 0, stream, w_out, woutb, nwo);
    // GEMM1: P = x @ w_in^T   (M=4096, N=6144, K=2048), bf16 out
    hipLaunchKernelGGL((gemm_bt<false>), dim3(48, 32, 1), blk, 0, stream, xObuf, winb, (void*)Pbuf, 6144, 2048);
    // Flash attention (x_bf16 dead now; O overwrites it)
    hipLaunchKernelGGL(attn_kernel, dim3(32, 16, 2), blk, 0, stream, Pbuf, xObuf);
    // GEMM2: out = O @ w_out^T (M=4096, N=2048, K=2048), fp32 out
    hipLaunchKernelGGL((gemm_bt<true>), dim3(16, 32, 1), blk, 0, stream, xObuf, woutb, (void*)out, 2048, 2048);
}

// Round 6
// 442.987 us; speedup vs baseline: 3.3343x; 1.5383x over previous
//
#include <hip/hip_runtime.h>
#include <hip/hip_bf16.h>
#include <math.h>

// Problem: Attention_58102317580396
// B=2, S=2048, D=2048, H=16, DH=128. Inputs/outputs FP32; internal bf16 MFMA.
// Pipeline: cvt(x,w_in,w_out)->bf16 ; gemm_bt(x,w_in)->P[4096][6144] ;
//           flash attn -> O[4096][2048] ; gemm_bt(O,w_out)->out fp32.
// R6 attn rewrite: S^T = K*Q^T (per-lane q -> 2-shfl softmax, scalar m/l),
// in-register P^T->B-frag via 8 shfl (no pTile LDS, no mid barrier),
// XOR-swizzled sK (kills 16-way conflicts), double-buffered K/V staging
// (1 barrier/iter), work-balanced qt mapping (co-resident qt + 31-qt).
// Verified layouts (learn_hip m89/m120):
//   A-frag: m=lane&15, k=quad*8+j ; B-frag: n=lane&15, k=quad*8+j (same addr)
//   C/D:    col=lane&15, row=quad*4+reg

typedef short bf16x8 __attribute__((ext_vector_type(8)));
typedef float f32x4 __attribute__((ext_vector_type(4)));

#define NEG_BIG -30000.0f

__device__ __forceinline__ short f2bf(float f) {
    union { float f; unsigned u; } v; v.f = f;
    unsigned r = v.u + 0x7fffu + ((v.u >> 16) & 1u);  // RNE
    return (short)(r >> 16);
}

__device__ __forceinline__ int pack2bf(float a, float b) {
    return (int)((((unsigned)f2bf(b)) << 16) | (((unsigned)f2bf(a)) & 0xffffu));
}

#define GLDS16(g, l) \
    __builtin_amdgcn_global_load_lds((const __attribute__((address_space(1))) void*)(g), \
                                     (__attribute__((address_space(3))) void*)(l), 16, 0, 0)

// fp32 -> bf16 elementwise (n divisible by 1024)
__global__ __launch_bounds__(256) void cvt_f32_bf16(const float* __restrict__ src,
                                                    short* __restrict__ dst, int n) {
    int i = (blockIdx.x * blockDim.x + threadIdx.x) * 4;
    if (i < n) {
        float4 v = *(const float4*)(src + i);
        short4 o;
        o.x = f2bf(v.x); o.y = f2bf(v.y); o.z = f2bf(v.z); o.w = f2bf(v.w);
        *(short4*)(dst + i) = o;
    }
}

// C[M][N] = A[M][K] * B[N][K]^T  (bf16 in, fp32 acc, bf16 or fp32 out)
// m97 structure: block 256 = 4 waves; block tile 128x128; wave tile 64x64.
template <bool F32OUT>
__global__ __launch_bounds__(256) void gemm_bt(const short* __restrict__ A,
                                               const short* __restrict__ Bm,
                                               void* __restrict__ Cv,
                                               int N, int K) {
    __shared__ short sA[128 * 32];
    __shared__ short sB[128 * 32];
    const int lane = threadIdx.x & 63;
    const int w = threadIdx.x >> 6;
    const int l15 = lane & 15, quad = lane >> 4;
    const int bm0 = blockIdx.y * 128, bn0 = blockIdx.x * 128;

    const int c1 = w * 64 + lane;
    const short* gA = A + (size_t)(bm0 + (c1 >> 2)) * K + (c1 & 3) * 8;
    const short* gB = Bm + (size_t)(bn0 + (c1 >> 2)) * K + (c1 & 3) * 8;
    const size_t half = (size_t)64 * K;
    short* lA1 = sA + w * 512;
    short* lA2 = sA + 2048 + w * 512;
    short* lB1 = sB + w * 512;
    short* lB2 = sB + 2048 + w * 512;

    const int wm = (w >> 1) * 64, wn = (w & 1) * 64;
    const short* pa = sA + (wm + l15) * 32 + quad * 8;
    const short* pb = sB + (wn + l15) * 32 + quad * 8;

    f32x4 acc[4][4] = {};
    for (int k0 = 0; k0 < K; k0 += 32) {
        GLDS16(gA + k0, lA1);
        GLDS16(gA + half + k0, lA2);
        GLDS16(gB + k0, lB1);
        GLDS16(gB + half + k0, lB2);
        __syncthreads();
        bf16x8 af[4], bf[4];
        #pragma unroll
        for (int mt = 0; mt < 4; mt++) af[mt] = *(const bf16x8*)(pa + mt * 512);
        #pragma unroll
        for (int nt = 0; nt < 4; nt++) bf[nt] = *(const bf16x8*)(pb + nt * 512);
        #pragma unroll
        for (int mt = 0; mt < 4; mt++)
            #pragma unroll
            for (int nt = 0; nt < 4; nt++)
                acc[mt][nt] = __builtin_amdgcn_mfma_f32_16x16x32_bf16(af[mt], bf[nt], acc[mt][nt], 0, 0, 0);
        __syncthreads();
    }
    #pragma unroll
    for (int mt = 0; mt < 4; mt++)
        #pragma unroll
        for (int nt = 0; nt < 4; nt++)
            #pragma unroll
            for (int r = 0; r < 4; r++) {
                int row = bm0 + wm + mt * 16 + quad * 4 + r;
                int col = bn0 + wn + nt * 16 + l15;
                if (F32OUT)
                    ((float*)Cv)[(size_t)row * N + col] = acc[mt][nt][r];
                else
                    ((short*)Cv)[(size_t)row * N + col] = f2bf(acc[mt][nt][r]);
            }
}

// Flash attention, causal, S^T formulation.
// grid = 1024 blocks 1D; decode b,h,t -> qt balanced so co-resident blocks
// (ids +256 apart) carry qt and 31-qt. 4 waves/block; wave owns 16 q-rows.
// sK: XOR-swizzled chunks (row, j' = j^(row&15)); sVt: [d][key] pitch 40.
#define VP 40
__global__ __launch_bounds__(256) void attn_kernel(const short* __restrict__ P,
                                                   short* __restrict__ O) {
    constexpr int S = 2048, ROWW = 6144, HD = 2048;
    const int id = blockIdx.x;
    const int b = id >> 9;
    const int rr = id & 511;
    const int h = rr & 15;
    const int t0 = rr >> 4;                       // 0..31
    const int qt = (t0 < 16) ? t0 : 47 - t0;      // balance: pair qt with 31-qt
    const int wave = threadIdx.x >> 6, lane = threadIdx.x & 63;
    const int l15 = lane & 15, quad = lane >> 4;
    const int qRow = qt * 64 + wave * 16;
    const short* Pb = P + (size_t)b * S * ROWW;
    const short* Qp = Pb + h * 384;
    const short* Kp = Qp + 128;
    const short* Vp = Qp + 256;

    __shared__ short sK[2][32 * 128];   // 2 x 8 KB, swizzled chunk layout
    __shared__ short sVt[2][128 * VP];  // 2 x 10 KB, [d][key]

    // Q fragments (B operand, n=q=l15, k=d=quad*8+j) — addressing identical to A-frag
    bf16x8 qf[4];
    #pragma unroll
    for (int f = 0; f < 4; f++)
        qf[f] = *(const bf16x8*)(Qp + (size_t)(qRow + l15) * ROWW + f * 32 + quad * 8);

    // K staging (GLDS): thread stages chunks c1 = wave*64+lane and c1+256.
    // LDS chunk c -> (row = c>>4, slot = c&15); global col j = slot ^ (row&15).
    const int c1 = wave * 64 + lane;
    const int krow1 = c1 >> 4;                            // wave*4 + (lane>>4)
    const int kcol = (((c1 & 15) ^ (krow1 & 15)) * 8);    // same for c1+256 (row+16)
    const short* gK1 = Kp + (size_t)krow1 * ROWW + kcol;
    const short* gK2 = Kp + (size_t)(krow1 + 16) * ROWW + kcol;
    const int ldsOff1 = wave * 512;       // shorts
    const int ldsOff2 = 2048 + wave * 512;

    // V staging: thread t -> key = t&31, d0 = (t>>5)*8 (and d0+64)
    const int tid = threadIdx.x;
    const int vKey = tid & 31;
    const int vD0 = (tid >> 5) * 8;
    const short* gV = Vp + (size_t)vKey * ROWW + vD0;

    const int kTiles = (qt * 2 + 2 < 64) ? (qt * 2 + 2) : 64;
    const float scale = 0.08838834764831845f;  // 1/sqrt(128)
    const int qG = qRow + l15;                 // this lane's q row

    f32x4 accO[8] = {};                        // O^T tile: row=d(quad*4+r), col=q(l15)
    float m_i = NEG_BIG, l_i = 0.f;

    // prologue: stage tile 0 into buffer 0
    GLDS16(gK1, &sK[0][ldsOff1]);
    GLDS16(gK2, &sK[0][ldsOff2]);
    {
        bf16x8 v0 = *(const bf16x8*)(gV);
        bf16x8 v1 = *(const bf16x8*)(gV + 64);
        #pragma unroll
        for (int j = 0; j < 8; j++) {
            sVt[0][(vD0 + j) * VP + vKey] = v0[j];
            sVt[0][(vD0 + 64 + j) * VP + vKey] = v1[j];
        }
    }
    __syncthreads();

    for (int kt = 0; kt < kTiles; kt++) {
        const int cur = kt & 1, nxt = cur ^ 1;
        const bool pre = (kt + 1 < kTiles);
        bf16x8 v0n, v1n;
        if (pre) {
            const size_t kOff = (size_t)(kt + 1) * 32 * ROWW;
            GLDS16(gK1 + kOff, &sK[nxt][ldsOff1]);
            GLDS16(gK2 + kOff, &sK[nxt][ldsOff2]);
            v0n = *(const bf16x8*)(gV + kOff);
            v1n = *(const bf16x8*)(gV + kOff + 64);
        }
        // QK^T transposed: sc[hh] = S^T tile, row=key(quad*4+r), col=q(l15)
        f32x4 sc[2] = {};
        #pragma unroll
        for (int hh = 0; hh < 2; hh++) {
            const int row = hh * 16 + l15;   // key row (A operand m=l15)
            #pragma unroll
            for (int f = 0; f < 4; f++) {
                const int jj = (4 * f + quad) ^ l15;  // de-swizzle chunk
                bf16x8 kf = *(const bf16x8*)(&sK[cur][row * 128 + jj * 8]);
                sc[hh] = __builtin_amdgcn_mfma_f32_16x16x32_bf16(kf, qf[f], sc[hh], 0, 0, 0);
            }
        }
        // scale + causal mask: key = kt*32 + hh*16 + quad*4 + r, q = qG
        #pragma unroll
        for (int hh = 0; hh < 2; hh++)
            #pragma unroll
            for (int r = 0; r < 4; r++) {
                int key = kt * 32 + hh * 16 + quad * 4 + r;
                float v = sc[hh][r] * scale;
                sc[hh][r] = (key <= qG) ? v : NEG_BIG;
            }
        // per-lane softmax over 8 local keys + 2-step quad reduction
        float mloc = sc[0][0];
        #pragma unroll
        for (int r = 1; r < 4; r++) mloc = fmaxf(mloc, sc[0][r]);
        #pragma unroll
        for (int r = 0; r < 4; r++) mloc = fmaxf(mloc, sc[1][r]);
        mloc = fmaxf(mloc, __shfl_xor(mloc, 16));
        mloc = fmaxf(mloc, __shfl_xor(mloc, 32));
        const float nm = fmaxf(m_i, mloc);
        const float alpha = __expf(m_i - nm);
        m_i = nm;
        float ssum = 0.f;
        #pragma unroll
        for (int hh = 0; hh < 2; hh++)
            #pragma unroll
            for (int r = 0; r < 4; r++) {
                float p = __expf(sc[hh][r] - nm);
                sc[hh][r] = p;
                ssum += p;
            }
        ssum += __shfl_xor(ssum, 16);
        ssum += __shfl_xor(ssum, 32);
        l_i = alpha * l_i + ssum;
        #pragma unroll
        for (int t = 0; t < 8; t++)
            #pragma unroll
            for (int r = 0; r < 4; r++) accO[t][r] *= alpha;
        // P^T (C-layout) -> B-frag via 8 shfl: dest lane (l15,q') needs keys
        // 8q'..8q'+7 = half (q'>>1), src quads 2(q'&1), 2(q'&1)+1, dwords 0,1.
        const int d00 = pack2bf(sc[0][0], sc[0][1]);
        const int d01 = pack2bf(sc[0][2], sc[0][3]);
        const int d10 = pack2bf(sc[1][0], sc[1][1]);
        const int d11 = pack2bf(sc[1][2], sc[1][3]);
        const int srcA = l15 + ((quad & 1) << 5);
        const int srcB = srcA + 16;
        const int s00 = __shfl(d00, srcA), s01 = __shfl(d01, srcA);
        const int s02 = __shfl(d00, srcB), s03 = __shfl(d01, srcB);
        const int s10 = __shfl(d10, srcA), s11 = __shfl(d11, srcA);
        const int s12 = __shfl(d10, srcB), s13 = __shfl(d11, srcB);
        union { int i[4]; bf16x8 v; } pu;
        const bool lo = quad < 2;
        pu.i[0] = lo ? s00 : s10;
        pu.i[1] = lo ? s01 : s11;
        pu.i[2] = lo ? s02 : s12;
        pu.i[3] = lo ? s03 : s13;
        const bf16x8 pf = pu.v;
        // PV: O^T += V^T * P^T ; A = V^T from sVt (m=d=l15, k=key=quad*8+j)
        #pragma unroll
        for (int t = 0; t < 8; t++) {
            bf16x8 vf = *(const bf16x8*)(&sVt[cur][(t * 16 + l15) * VP + quad * 8]);
            accO[t] = __builtin_amdgcn_mfma_f32_16x16x32_bf16(vf, pf, accO[t], 0, 0, 0);
        }
        // commit prefetched V into next buffer
        if (pre) {
            #pragma unroll
            for (int j = 0; j < 8; j++) {
                sVt[nxt][(vD0 + j) * VP + vKey] = v0n[j];
                sVt[nxt][(vD0 + 64 + j) * VP + vKey] = v1n[j];
            }
        }
        __syncthreads();  // one barrier/iter: drains GLDS + orders buffer swap
    }
    // epilogue: O[q][d] from O^T regs; 4 consecutive d per store (short4)
    const float inv = 1.0f / l_i;
    #pragma unroll
    for (int t = 0; t < 8; t++) {
        short4 st;
        st.x = f2bf(accO[t][0] * inv);
        st.y = f2bf(accO[t][1] * inv);
        st.z = f2bf(accO[t][2] * inv);
        st.w = f2bf(accO[t][3] * inv);
        *(short4*)(&O[(size_t)(b * S + qG) * HD + h * 128 + t * 16 + quad * 4]) = st;
    }
}

extern "C" void kernel_launch(void* const* d_in, const int* in_sizes, int n_in,
                              void* d_out, int out_size, void* d_ws, size_t ws_size,
                              hipStream_t stream) {
    const float* x     = (const float*)d_in[0];  // [2,2048,2048] fp32
    const float* w_in  = (const float*)d_in[1];  // [6144,2048]  fp32
    const float* w_out = (const float*)d_in[2];  // [2048,2048]  fp32
    float* out = (float*)d_out;                  // [2,2048,2048] fp32

    // Workspace (96 MiB): P[4096*6144] bf16 | xO[8388608] bf16 (x_bf16 then O)
    //                     | w_in_b[6144*2048] bf16 | w_out_b[2048*2048] bf16
    short* Pbuf   = (short*)d_ws;
    short* xObuf  = Pbuf  + (size_t)4096 * 6144;
    short* winb   = xObuf + (size_t)8388608;
    short* woutb  = winb  + (size_t)6144 * 2048;

    dim3 blk(256, 1, 1);
    const int nx = 2 * 2048 * 2048, nwi = 6144 * 2048, nwo = 2048 * 2048;
    hipLaunchKernelGGL(cvt_f32_bf16, dim3(nx / 1024), blk, 0, stream, x, xObuf, nx);
    hipLaunchKernelGGL(cvt_f32_bf16, dim3(nwi / 1024), blk, 0, stream, w_in, winb, nwi);
    hipLaunchKernelGGL(cvt_f32_bf16, dim3(nwo / 1024), blk, 0, stream, w_out, woutb, nwo);
    // GEMM1: P = x @ w_in^T   (M=4096, N=6144, K=2048), bf16 out
    hipLaunchKernelGGL((gemm_bt<false>), dim3(48, 32, 1), blk, 0, stream, xObuf, winb, (void*)Pbuf, 6144, 2048);
    // Flash attention (x_bf16 dead now; O overwrites it)
    hipLaunchKernelGGL(attn_kernel, dim3(1024, 1, 1), blk, 0, stream, Pbuf, xObuf);
    // GEMM2: out = O @ w_out^T (M=4096, N=2048, K=2048), fp32 out
    hipLaunchKernelGGL((gemm_bt<true>), dim3(16, 32, 1), blk, 0, stream, xObuf, woutb, (void*)out, 2048, 2048);
}

// Round 7
// 414.123 us; speedup vs baseline: 3.5667x; 1.0697x over previous
//
#include <hip/hip_runtime.h>
#include <hip/hip_bf16.h>
#include <math.h>

// Problem: Attention_58102317580396
// B=2, S=2048, D=2048, H=16, DH=128. Inputs/outputs FP32; internal bf16 MFMA.
// Pipeline: cvt(x,w_in,w_out)->bf16 ; gemm_bt(x,w_in)->P[4096][6144] ;
//           flash attn -> O[4096][2048] ; gemm_bt(O,w_out)->out fp32.
// R7: (1) attn q-tile 128 rows / 512 threads / 8 waves — halves KV LDS-staging
// traffic + barrier drains; waves 0-3 stage K (GLDS), waves 4-7 stage V.
// (2) gemm_bt templated on BN; GEMM2 uses BN=64 -> 1024 blocks (4/CU, was 2).
// Verified layouts (learn_hip m89/m120):
//   A-frag: m=lane&15, k=quad*8+j ; B-frag: n=lane&15, k=quad*8+j (same addr)
//   C/D:    col=lane&15, row=quad*4+reg

typedef short bf16x8 __attribute__((ext_vector_type(8)));
typedef float f32x4 __attribute__((ext_vector_type(4)));

#define NEG_BIG -30000.0f

__device__ __forceinline__ short f2bf(float f) {
    union { float f; unsigned u; } v; v.f = f;
    unsigned r = v.u + 0x7fffu + ((v.u >> 16) & 1u);  // RNE
    return (short)(r >> 16);
}

__device__ __forceinline__ int pack2bf(float a, float b) {
    return (int)((((unsigned)f2bf(b)) << 16) | (((unsigned)f2bf(a)) & 0xffffu));
}

#define GLDS16(g, l) \
    __builtin_amdgcn_global_load_lds((const __attribute__((address_space(1))) void*)(g), \
                                     (__attribute__((address_space(3))) void*)(l), 16, 0, 0)

// fp32 -> bf16 elementwise (n divisible by 1024)
__global__ __launch_bounds__(256) void cvt_f32_bf16(const float* __restrict__ src,
                                                    short* __restrict__ dst, int n) {
    int i = (blockIdx.x * blockDim.x + threadIdx.x) * 4;
    if (i < n) {
        float4 v = *(const float4*)(src + i);
        short4 o;
        o.x = f2bf(v.x); o.y = f2bf(v.y); o.z = f2bf(v.z); o.w = f2bf(v.w);
        *(short4*)(dst + i) = o;
    }
}

// C[M][N] = A[M][K] * B[N][K]^T  (bf16 in, fp32 acc, bf16 or fp32 out)
// block 256 = 4 waves; block tile 128xBN; wave tile 64x(BN/2).
template <int BN, bool F32OUT>
__global__ __launch_bounds__(256) void gemm_bt(const short* __restrict__ A,
                                               const short* __restrict__ Bm,
                                               void* __restrict__ Cv,
                                               int N, int K) {
    constexpr int NT = BN / 32;          // n-acc tiles per wave
    __shared__ short sA[128 * 32];
    __shared__ short sB[BN * 32];
    const int lane = threadIdx.x & 63;
    const int w = threadIdx.x >> 6;
    const int l15 = lane & 15, quad = lane >> 4;
    const int bm0 = blockIdx.y * 128, bn0 = blockIdx.x * BN;

    const int c1 = w * 64 + lane;        // chunk id 0..255
    const short* gA = A + (size_t)(bm0 + (c1 >> 2)) * K + (c1 & 3) * 8;
    const short* gB = Bm + (size_t)(bn0 + (c1 >> 2)) * K + (c1 & 3) * 8;
    const size_t halfA = (size_t)64 * K;
    short* lA1 = sA + w * 512;
    short* lA2 = sA + 2048 + w * 512;
    short* lB1 = sB + w * 512;
    short* lB2 = sB + 2048 + w * 512;    // only used when BN==128

    const int wm = (w >> 1) * 64, wn = (w & 1) * (BN / 2);
    const short* pa = sA + (wm + l15) * 32 + quad * 8;
    const short* pb = sB + (wn + l15) * 32 + quad * 8;

    f32x4 acc[4][NT] = {};
    for (int k0 = 0; k0 < K; k0 += 32) {
        GLDS16(gA + k0, lA1);
        GLDS16(gA + halfA + k0, lA2);
        GLDS16(gB + k0, lB1);
        if constexpr (BN == 128) GLDS16(gB + halfA + k0, lB2);
        __syncthreads();
        bf16x8 af[4], bf[NT];
        #pragma unroll
        for (int mt = 0; mt < 4; mt++) af[mt] = *(const bf16x8*)(pa + mt * 512);
        #pragma unroll
        for (int nt = 0; nt < NT; nt++) bf[nt] = *(const bf16x8*)(pb + nt * 512);
        #pragma unroll
        for (int mt = 0; mt < 4; mt++)
            #pragma unroll
            for (int nt = 0; nt < NT; nt++)
                acc[mt][nt] = __builtin_amdgcn_mfma_f32_16x16x32_bf16(af[mt], bf[nt], acc[mt][nt], 0, 0, 0);
        __syncthreads();
    }
    #pragma unroll
    for (int mt = 0; mt < 4; mt++)
        #pragma unroll
        for (int nt = 0; nt < NT; nt++)
            #pragma unroll
            for (int r = 0; r < 4; r++) {
                int row = bm0 + wm + mt * 16 + quad * 4 + r;
                int col = bn0 + wn + nt * 16 + l15;
                if (F32OUT)
                    ((float*)Cv)[(size_t)row * N + col] = acc[mt][nt][r];
                else
                    ((short*)Cv)[(size_t)row * N + col] = f2bf(acc[mt][nt][r]);
            }
}

// Flash attention, causal, S^T formulation. q-tile 128 rows, 8 waves (512 thr).
// grid = 512 blocks; qt = b ? 15-t0 : t0 so co-resident pairs (ids +256) do
// constant 68 tiles. Waves 0-3 stage K (GLDS, XOR-swizzled), waves 4-7 stage V
// (transposed, pitch 40). Per-wave compute identical to R6 (16 q-rows/wave).
#define VP 40
__global__ __launch_bounds__(512) void attn_kernel(const short* __restrict__ P,
                                                   short* __restrict__ O) {
    constexpr int S = 2048, ROWW = 6144, HD = 2048;
    const int id = blockIdx.x;
    const int b = id >> 8;
    const int rr = id & 255;
    const int h = rr & 15;
    const int t0 = rr >> 4;                    // 0..15
    const int qt = b ? (15 - t0) : t0;         // work balance across pairs
    const int wave = threadIdx.x >> 6, lane = threadIdx.x & 63;
    const int l15 = lane & 15, quad = lane >> 4;
    const int qRow = qt * 128 + wave * 16;
    const short* Pb = P + (size_t)b * S * ROWW;
    const short* Qp = Pb + h * 384;
    const short* Kp = Qp + 128;
    const short* Vp = Qp + 256;

    __shared__ short sK[2][32 * 128];   // swizzled chunk layout
    __shared__ short sVt[2][128 * VP];  // [d][key]

    // Q fragments (B operand, n=q=l15, k=d=quad*8+j)
    bf16x8 qf[4];
    #pragma unroll
    for (int f = 0; f < 4; f++)
        qf[f] = *(const bf16x8*)(Qp + (size_t)(qRow + l15) * ROWW + f * 32 + quad * 8);

    const bool isK = wave < 4;
    // K staging (waves 0-3): chunks c1, c1+256. chunk c -> (row=c>>4, slot=c&15),
    // global col j = slot ^ (row&15).
    const int c1 = (wave & 3) * 64 + lane;
    const int krow1 = c1 >> 4;
    const int kcol = ((c1 & 15) ^ (krow1 & 15)) * 8;
    const short* gK1 = Kp + (size_t)krow1 * ROWW + kcol;
    const short* gK2 = Kp + (size_t)(krow1 + 16) * ROWW + kcol;
    const int ldsOff1 = (wave & 3) * 512;
    const int ldsOff2 = 2048 + (wave & 3) * 512;
    // V staging (waves 4-7): vt = tid-256 -> key = vt&31, d0 = (vt>>5)*8 (and +64)
    const int vt = (int)threadIdx.x - 256;
    const int vKey = vt & 31;
    const int vD0 = (vt >> 5) * 8;
    const short* gV = Vp + (size_t)vKey * ROWW + vD0;

    const int kTiles = qt * 4 + 4;             // covers keys 0 .. qt*128+127
    const float scale = 0.08838834764831845f;  // 1/sqrt(128)
    const int qG = qRow + l15;

    f32x4 accO[8] = {};                        // O^T: row=d(quad*4+r), col=q(l15)
    float m_i = NEG_BIG, l_i = 0.f;

    // prologue: stage tile 0 into buffer 0
    if (isK) {
        GLDS16(gK1, &sK[0][ldsOff1]);
        GLDS16(gK2, &sK[0][ldsOff2]);
    } else {
        bf16x8 v0 = *(const bf16x8*)(gV);
        bf16x8 v1 = *(const bf16x8*)(gV + 64);
        #pragma unroll
        for (int j = 0; j < 8; j++) {
            sVt[0][(vD0 + j) * VP + vKey] = v0[j];
            sVt[0][(vD0 + 64 + j) * VP + vKey] = v1[j];
        }
    }
    __syncthreads();

    for (int kt = 0; kt < kTiles; kt++) {
        const int cur = kt & 1, nxt = cur ^ 1;
        const bool pre = (kt + 1 < kTiles);
        bf16x8 v0n, v1n;
        if (pre) {
            const size_t kOff = (size_t)(kt + 1) * 32 * ROWW;
            if (isK) {
                GLDS16(gK1 + kOff, &sK[nxt][ldsOff1]);
                GLDS16(gK2 + kOff, &sK[nxt][ldsOff2]);
            } else {
                v0n = *(const bf16x8*)(gV + kOff);
                v1n = *(const bf16x8*)(gV + kOff + 64);
            }
        }
        // QK^T transposed: sc[hh] row=key(quad*4+r), col=q(l15)
        f32x4 sc[2] = {};
        #pragma unroll
        for (int hh = 0; hh < 2; hh++) {
            const int row = hh * 16 + l15;
            #pragma unroll
            for (int f = 0; f < 4; f++) {
                const int jj = (4 * f + quad) ^ l15;
                bf16x8 kf = *(const bf16x8*)(&sK[cur][row * 128 + jj * 8]);
                sc[hh] = __builtin_amdgcn_mfma_f32_16x16x32_bf16(kf, qf[f], sc[hh], 0, 0, 0);
            }
        }
        // scale + causal mask
        #pragma unroll
        for (int hh = 0; hh < 2; hh++)
            #pragma unroll
            for (int r = 0; r < 4; r++) {
                int key = kt * 32 + hh * 16 + quad * 4 + r;
                float v = sc[hh][r] * scale;
                sc[hh][r] = (key <= qG) ? v : NEG_BIG;
            }
        // per-lane softmax + 2-step quad reduction
        float mloc = sc[0][0];
        #pragma unroll
        for (int r = 1; r < 4; r++) mloc = fmaxf(mloc, sc[0][r]);
        #pragma unroll
        for (int r = 0; r < 4; r++) mloc = fmaxf(mloc, sc[1][r]);
        mloc = fmaxf(mloc, __shfl_xor(mloc, 16));
        mloc = fmaxf(mloc, __shfl_xor(mloc, 32));
        const float nm = fmaxf(m_i, mloc);
        const float alpha = __expf(m_i - nm);
        m_i = nm;
        float ssum = 0.f;
        #pragma unroll
        for (int hh = 0; hh < 2; hh++)
            #pragma unroll
            for (int r = 0; r < 4; r++) {
                float p = __expf(sc[hh][r] - nm);
                sc[hh][r] = p;
                ssum += p;
            }
        ssum += __shfl_xor(ssum, 16);
        ssum += __shfl_xor(ssum, 32);
        l_i = alpha * l_i + ssum;
        #pragma unroll
        for (int t = 0; t < 8; t++)
            #pragma unroll
            for (int r = 0; r < 4; r++) accO[t][r] *= alpha;
        // P^T (C-layout) -> B-frag via 8 shfl
        const int d00 = pack2bf(sc[0][0], sc[0][1]);
        const int d01 = pack2bf(sc[0][2], sc[0][3]);
        const int d10 = pack2bf(sc[1][0], sc[1][1]);
        const int d11 = pack2bf(sc[1][2], sc[1][3]);
        const int srcA = l15 + ((quad & 1) << 5);
        const int srcB = srcA + 16;
        const int s00 = __shfl(d00, srcA), s01 = __shfl(d01, srcA);
        const int s02 = __shfl(d00, srcB), s03 = __shfl(d01, srcB);
        const int s10 = __shfl(d10, srcA), s11 = __shfl(d11, srcA);
        const int s12 = __shfl(d10, srcB), s13 = __shfl(d11, srcB);
        union { int i[4]; bf16x8 v; } pu;
        const bool lo = quad < 2;
        pu.i[0] = lo ? s00 : s10;
        pu.i[1] = lo ? s01 : s11;
        pu.i[2] = lo ? s02 : s12;
        pu.i[3] = lo ? s03 : s13;
        const bf16x8 pf = pu.v;
        // PV: O^T += V^T * P^T ; A = V^T from sVt (m=d=l15, k=key=quad*8+j)
        #pragma unroll
        for (int t = 0; t < 8; t++) {
            bf16x8 vf = *(const bf16x8*)(&sVt[cur][(t * 16 + l15) * VP + quad * 8]);
            accO[t] = __builtin_amdgcn_mfma_f32_16x16x32_bf16(vf, pf, accO[t], 0, 0, 0);
        }
        // commit prefetched V into next buffer
        if (pre && !isK) {
            #pragma unroll
            for (int j = 0; j < 8; j++) {
                sVt[nxt][(vD0 + j) * VP + vKey] = v0n[j];
                sVt[nxt][(vD0 + 64 + j) * VP + vKey] = v1n[j];
            }
        }
        __syncthreads();  // one barrier/iter: drains GLDS + orders buffer swap
    }
    // epilogue: O[q][d], 4 consecutive d per short4 store
    const float inv = 1.0f / l_i;
    #pragma unroll
    for (int t = 0; t < 8; t++) {
        short4 st;
        st.x = f2bf(accO[t][0] * inv);
        st.y = f2bf(accO[t][1] * inv);
        st.z = f2bf(accO[t][2] * inv);
        st.w = f2bf(accO[t][3] * inv);
        *(short4*)(&O[(size_t)(b * S + qG) * HD + h * 128 + t * 16 + quad * 4]) = st;
    }
}

extern "C" void kernel_launch(void* const* d_in, const int* in_sizes, int n_in,
                              void* d_out, int out_size, void* d_ws, size_t ws_size,
                              hipStream_t stream) {
    const float* x     = (const float*)d_in[0];  // [2,2048,2048] fp32
    const float* w_in  = (const float*)d_in[1];  // [6144,2048]  fp32
    const float* w_out = (const float*)d_in[2];  // [2048,2048]  fp32
    float* out = (float*)d_out;                  // [2,2048,2048] fp32

    // Workspace (96 MiB): P[4096*6144] bf16 | xO[8388608] bf16 (x_bf16 then O)
    //                     | w_in_b[6144*2048] bf16 | w_out_b[2048*2048] bf16
    short* Pbuf   = (short*)d_ws;
    short* xObuf  = Pbuf  + (size_t)4096 * 6144;
    short* winb   = xObuf + (size_t)8388608;
    short* woutb  = winb  + (size_t)6144 * 2048;

    dim3 blk(256, 1, 1);
    const int nx = 2 * 2048 * 2048, nwi = 6144 * 2048, nwo = 2048 * 2048;
    hipLaunchKernelGGL(cvt_f32_bf16, dim3(nx / 1024), blk, 0, stream, x, xObuf, nx);
    hipLaunchKernelGGL(cvt_f32_bf16, dim3(nwi / 1024), blk, 0, stream, w_in, winb, nwi);
    hipLaunchKernelGGL(cvt_f32_bf16, dim3(nwo / 1024), blk, 0, stream, w_out, woutb, nwo);
    // GEMM1: P = x @ w_in^T   (M=4096, N=6144, K=2048), bf16 out, BN=128
    hipLaunchKernelGGL((gemm_bt<128, false>), dim3(48, 32, 1), blk, 0, stream, xObuf, winb, (void*)Pbuf, 6144, 2048);
    // Flash attention (x_bf16 dead now; O overwrites it), 512 blocks x 512 thr
    hipLaunchKernelGGL(attn_kernel, dim3(512, 1, 1), dim3(512, 1, 1), 0, stream, Pbuf, xObuf);
    // GEMM2: out = O @ w_out^T (M=4096, N=2048, K=2048), fp32 out, BN=64
    hipLaunchKernelGGL((gemm_bt<64, true>), dim3(32, 32, 1), blk, 0, stream, xObuf, woutb, (void*)out, 2048, 2048);
}

// Round 8
// 398.146 us; speedup vs baseline: 3.7098x; 1.0401x over previous
//
#include <hip/hip_runtime.h>
#include <hip/hip_bf16.h>
#include <math.h>

// Problem: Attention_58102317580396
// B=2, S=2048, D=2048, H=16, DH=128. Inputs/outputs FP32; internal bf16 MFMA.
// Pipeline: cvt(x,w_in,w_out)->bf16 ; gemm_bt(x,w_in)->P[4096][6144] ;
//           flash attn -> O[4096][2048] ; gemm_bt(O,w_out)->out fp32.
// R8: gemm_bt BK=64 — two 32-k sub-tiles staged per barrier pair, 32 MFMA per
// barrier (BN=128; AITER-style density). Halves K-loop barrier count (the
// dominant stall at K=2048). LDS 32 KB (BN=128) / 24 KB (BN=64). Attn
// unchanged from R7 (isolate GEMM delta; attn enters top-5 for counters).
// Verified layouts (learn_hip m89/m120):
//   A-frag: m=lane&15, k=quad*8+j ; B-frag: n=lane&15, k=quad*8+j (same addr)
//   C/D:    col=lane&15, row=quad*4+reg

typedef short bf16x8 __attribute__((ext_vector_type(8)));
typedef float f32x4 __attribute__((ext_vector_type(4)));

#define NEG_BIG -30000.0f

__device__ __forceinline__ short f2bf(float f) {
    union { float f; unsigned u; } v; v.f = f;
    unsigned r = v.u + 0x7fffu + ((v.u >> 16) & 1u);  // RNE
    return (short)(r >> 16);
}

__device__ __forceinline__ int pack2bf(float a, float b) {
    return (int)((((unsigned)f2bf(b)) << 16) | (((unsigned)f2bf(a)) & 0xffffu));
}

#define GLDS16(g, l) \
    __builtin_amdgcn_global_load_lds((const __attribute__((address_space(1))) void*)(g), \
                                     (__attribute__((address_space(3))) void*)(l), 16, 0, 0)

// fp32 -> bf16 elementwise (n divisible by 1024)
__global__ __launch_bounds__(256) void cvt_f32_bf16(const float* __restrict__ src,
                                                    short* __restrict__ dst, int n) {
    int i = (blockIdx.x * blockDim.x + threadIdx.x) * 4;
    if (i < n) {
        float4 v = *(const float4*)(src + i);
        short4 o;
        o.x = f2bf(v.x); o.y = f2bf(v.y); o.z = f2bf(v.z); o.w = f2bf(v.w);
        *(short4*)(dst + i) = o;
    }
}

// C[M][N] = A[M][K] * B[N][K]^T  (bf16 in, fp32 acc, bf16 or fp32 out)
// block 256 = 4 waves; block tile 128xBN; wave tile 64x(BN/2); BK=64 as two
// 32-k sub-tiles per barrier pair. LDS layout per sub: chunk-ordered rows x32.
template <int BN, bool F32OUT>
__global__ __launch_bounds__(256) void gemm_bt(const short* __restrict__ A,
                                               const short* __restrict__ Bm,
                                               void* __restrict__ Cv,
                                               int N, int K) {
    constexpr int NT = BN / 32;               // n-acc tiles per wave
    constexpr int SUBA = 128 * 32;            // shorts per A sub-tile
    constexpr int SUBB = BN * 32;             // shorts per B sub-tile
    __shared__ short sA[2 * SUBA];
    __shared__ short sB[2 * SUBB];
    const int lane = threadIdx.x & 63;
    const int w = threadIdx.x >> 6;
    const int l15 = lane & 15, quad = lane >> 4;
    const int bm0 = blockIdx.y * 128, bn0 = blockIdx.x * BN;

    const int c1 = w * 64 + lane;             // chunk id 0..255
    const short* gA = A + (size_t)(bm0 + (c1 >> 2)) * K + (c1 & 3) * 8;
    const short* gB = Bm + (size_t)(bn0 + (c1 >> 2)) * K + (c1 & 3) * 8;
    const size_t half64 = (size_t)64 * K;     // chunk +256 -> row +64
    short* lA1 = sA + w * 512;                // wave-uniform GLDS bases
    short* lA2 = sA + 2048 + w * 512;
    short* lB1 = sB + w * 512;
    short* lB2 = sB + 2048 + w * 512;         // only when BN==128

    const int wm = (w >> 1) * 64, wn = (w & 1) * (BN / 2);
    const short* pa = sA + (wm + l15) * 32 + quad * 8;
    const short* pb = sB + (wn + l15) * 32 + quad * 8;

    f32x4 acc[4][NT] = {};
    for (int k0 = 0; k0 < K; k0 += 64) {
        #pragma unroll
        for (int s = 0; s < 2; s++) {
            const int ks = k0 + s * 32;
            GLDS16(gA + ks, lA1 + s * SUBA);
            GLDS16(gA + half64 + ks, lA2 + s * SUBA);
            GLDS16(gB + ks, lB1 + s * SUBB);
            if constexpr (BN == 128) GLDS16(gB + half64 + ks, lB2 + s * SUBB);
        }
        __syncthreads();
        #pragma unroll
        for (int s = 0; s < 2; s++) {
            bf16x8 af[4], bf[NT];
            #pragma unroll
            for (int mt = 0; mt < 4; mt++) af[mt] = *(const bf16x8*)(pa + s * SUBA + mt * 512);
            #pragma unroll
            for (int nt = 0; nt < NT; nt++) bf[nt] = *(const bf16x8*)(pb + s * SUBB + nt * 512);
            #pragma unroll
            for (int mt = 0; mt < 4; mt++)
                #pragma unroll
                for (int nt = 0; nt < NT; nt++)
                    acc[mt][nt] = __builtin_amdgcn_mfma_f32_16x16x32_bf16(af[mt], bf[nt], acc[mt][nt], 0, 0, 0);
        }
        __syncthreads();
    }
    #pragma unroll
    for (int mt = 0; mt < 4; mt++)
        #pragma unroll
        for (int nt = 0; nt < NT; nt++)
            #pragma unroll
            for (int r = 0; r < 4; r++) {
                int row = bm0 + wm + mt * 16 + quad * 4 + r;
                int col = bn0 + wn + nt * 16 + l15;
                if (F32OUT)
                    ((float*)Cv)[(size_t)row * N + col] = acc[mt][nt][r];
                else
                    ((short*)Cv)[(size_t)row * N + col] = f2bf(acc[mt][nt][r]);
            }
}

// Flash attention, causal, S^T formulation. q-tile 128 rows, 8 waves (512 thr).
// grid = 512 blocks; qt = b ? 15-t0 : t0 so co-resident pairs (ids +256) do
// constant 68 tiles. Waves 0-3 stage K (GLDS, XOR-swizzled), waves 4-7 stage V
// (transposed, pitch 40). Per-wave compute: 16 q-rows, S^T tiles.
#define VP 40
__global__ __launch_bounds__(512) void attn_kernel(const short* __restrict__ P,
                                                   short* __restrict__ O) {
    constexpr int S = 2048, ROWW = 6144, HD = 2048;
    const int id = blockIdx.x;
    const int b = id >> 8;
    const int rr = id & 255;
    const int h = rr & 15;
    const int t0 = rr >> 4;                    // 0..15
    const int qt = b ? (15 - t0) : t0;         // work balance across pairs
    const int wave = threadIdx.x >> 6, lane = threadIdx.x & 63;
    const int l15 = lane & 15, quad = lane >> 4;
    const int qRow = qt * 128 + wave * 16;
    const short* Pb = P + (size_t)b * S * ROWW;
    const short* Qp = Pb + h * 384;
    const short* Kp = Qp + 128;
    const short* Vp = Qp + 256;

    __shared__ short sK[2][32 * 128];   // swizzled chunk layout
    __shared__ short sVt[2][128 * VP];  // [d][key]

    // Q fragments (B operand, n=q=l15, k=d=quad*8+j)
    bf16x8 qf[4];
    #pragma unroll
    for (int f = 0; f < 4; f++)
        qf[f] = *(const bf16x8*)(Qp + (size_t)(qRow + l15) * ROWW + f * 32 + quad * 8);

    const bool isK = wave < 4;
    const int c1 = (wave & 3) * 64 + lane;
    const int krow1 = c1 >> 4;
    const int kcol = ((c1 & 15) ^ (krow1 & 15)) * 8;
    const short* gK1 = Kp + (size_t)krow1 * ROWW + kcol;
    const short* gK2 = Kp + (size_t)(krow1 + 16) * ROWW + kcol;
    const int ldsOff1 = (wave & 3) * 512;
    const int ldsOff2 = 2048 + (wave & 3) * 512;
    const int vt = (int)threadIdx.x - 256;
    const int vKey = vt & 31;
    const int vD0 = (vt >> 5) * 8;
    const short* gV = Vp + (size_t)vKey * ROWW + vD0;

    const int kTiles = qt * 4 + 4;
    const float scale = 0.08838834764831845f;  // 1/sqrt(128)
    const int qG = qRow + l15;

    f32x4 accO[8] = {};                        // O^T: row=d(quad*4+r), col=q(l15)
    float m_i = NEG_BIG, l_i = 0.f;

    if (isK) {
        GLDS16(gK1, &sK[0][ldsOff1]);
        GLDS16(gK2, &sK[0][ldsOff2]);
    } else {
        bf16x8 v0 = *(const bf16x8*)(gV);
        bf16x8 v1 = *(const bf16x8*)(gV + 64);
        #pragma unroll
        for (int j = 0; j < 8; j++) {
            sVt[0][(vD0 + j) * VP + vKey] = v0[j];
            sVt[0][(vD0 + 64 + j) * VP + vKey] = v1[j];
        }
    }
    __syncthreads();

    for (int kt = 0; kt < kTiles; kt++) {
        const int cur = kt & 1, nxt = cur ^ 1;
        const bool pre = (kt + 1 < kTiles);
        bf16x8 v0n, v1n;
        if (pre) {
            const size_t kOff = (size_t)(kt + 1) * 32 * ROWW;
            if (isK) {
                GLDS16(gK1 + kOff, &sK[nxt][ldsOff1]);
                GLDS16(gK2 + kOff, &sK[nxt][ldsOff2]);
            } else {
                v0n = *(const bf16x8*)(gV + kOff);
                v1n = *(const bf16x8*)(gV + kOff + 64);
            }
        }
        // QK^T transposed: sc[hh] row=key(quad*4+r), col=q(l15)
        f32x4 sc[2] = {};
        #pragma unroll
        for (int hh = 0; hh < 2; hh++) {
            const int row = hh * 16 + l15;
            #pragma unroll
            for (int f = 0; f < 4; f++) {
                const int jj = (4 * f + quad) ^ l15;
                bf16x8 kf = *(const bf16x8*)(&sK[cur][row * 128 + jj * 8]);
                sc[hh] = __builtin_amdgcn_mfma_f32_16x16x32_bf16(kf, qf[f], sc[hh], 0, 0, 0);
            }
        }
        #pragma unroll
        for (int hh = 0; hh < 2; hh++)
            #pragma unroll
            for (int r = 0; r < 4; r++) {
                int key = kt * 32 + hh * 16 + quad * 4 + r;
                float v = sc[hh][r] * scale;
                sc[hh][r] = (key <= qG) ? v : NEG_BIG;
            }
        float mloc = sc[0][0];
        #pragma unroll
        for (int r = 1; r < 4; r++) mloc = fmaxf(mloc, sc[0][r]);
        #pragma unroll
        for (int r = 0; r < 4; r++) mloc = fmaxf(mloc, sc[1][r]);
        mloc = fmaxf(mloc, __shfl_xor(mloc, 16));
        mloc = fmaxf(mloc, __shfl_xor(mloc, 32));
        const float nm = fmaxf(m_i, mloc);
        const float alpha = __expf(m_i - nm);
        m_i = nm;
        float ssum = 0.f;
        #pragma unroll
        for (int hh = 0; hh < 2; hh++)
            #pragma unroll
            for (int r = 0; r < 4; r++) {
                float p = __expf(sc[hh][r] - nm);
                sc[hh][r] = p;
                ssum += p;
            }
        ssum += __shfl_xor(ssum, 16);
        ssum += __shfl_xor(ssum, 32);
        l_i = alpha * l_i + ssum;
        #pragma unroll
        for (int t = 0; t < 8; t++)
            #pragma unroll
            for (int r = 0; r < 4; r++) accO[t][r] *= alpha;
        // P^T (C-layout) -> B-frag via 8 shfl
        const int d00 = pack2bf(sc[0][0], sc[0][1]);
        const int d01 = pack2bf(sc[0][2], sc[0][3]);
        const int d10 = pack2bf(sc[1][0], sc[1][1]);
        const int d11 = pack2bf(sc[1][2], sc[1][3]);
        const int srcA = l15 + ((quad & 1) << 5);
        const int srcB = srcA + 16;
        const int s00 = __shfl(d00, srcA), s01 = __shfl(d01, srcA);
        const int s02 = __shfl(d00, srcB), s03 = __shfl(d01, srcB);
        const int s10 = __shfl(d10, srcA), s11 = __shfl(d11, srcA);
        const int s12 = __shfl(d10, srcB), s13 = __shfl(d11, srcB);
        union { int i[4]; bf16x8 v; } pu;
        const bool lo = quad < 2;
        pu.i[0] = lo ? s00 : s10;
        pu.i[1] = lo ? s01 : s11;
        pu.i[2] = lo ? s02 : s12;
        pu.i[3] = lo ? s03 : s13;
        const bf16x8 pf = pu.v;
        // PV: O^T += V^T * P^T
        #pragma unroll
        for (int t = 0; t < 8; t++) {
            bf16x8 vf = *(const bf16x8*)(&sVt[cur][(t * 16 + l15) * VP + quad * 8]);
            accO[t] = __builtin_amdgcn_mfma_f32_16x16x32_bf16(vf, pf, accO[t], 0, 0, 0);
        }
        if (pre && !isK) {
            #pragma unroll
            for (int j = 0; j < 8; j++) {
                sVt[nxt][(vD0 + j) * VP + vKey] = v0n[j];
                sVt[nxt][(vD0 + 64 + j) * VP + vKey] = v1n[j];
            }
        }
        __syncthreads();
    }
    const float inv = 1.0f / l_i;
    #pragma unroll
    for (int t = 0; t < 8; t++) {
        short4 st;
        st.x = f2bf(accO[t][0] * inv);
        st.y = f2bf(accO[t][1] * inv);
        st.z = f2bf(accO[t][2] * inv);
        st.w = f2bf(accO[t][3] * inv);
        *(short4*)(&O[(size_t)(b * S + qG) * HD + h * 128 + t * 16 + quad * 4]) = st;
    }
}

extern "C" void kernel_launch(void* const* d_in, const int* in_sizes, int n_in,
                              void* d_out, int out_size, void* d_ws, size_t ws_size,
                              hipStream_t stream) {
    const float* x     = (const float*)d_in[0];  // [2,2048,2048] fp32
    const float* w_in  = (const float*)d_in[1];  // [6144,2048]  fp32
    const float* w_out = (const float*)d_in[2];  // [2048,2048]  fp32
    float* out = (float*)d_out;                  // [2,2048,2048] fp32

    // Workspace (96 MiB): P[4096*6144] bf16 | xO[8388608] bf16 (x_bf16 then O)
    //                     | w_in_b[6144*2048] bf16 | w_out_b[2048*2048] bf16
    short* Pbuf   = (short*)d_ws;
    short* xObuf  = Pbuf  + (size_t)4096 * 6144;
    short* winb   = xObuf + (size_t)8388608;
    short* woutb  = winb  + (size_t)6144 * 2048;

    dim3 blk(256, 1, 1);
    const int nx = 2 * 2048 * 2048, nwi = 6144 * 2048, nwo = 2048 * 2048;
    hipLaunchKernelGGL(cvt_f32_bf16, dim3(nx / 1024), blk, 0, stream, x, xObuf, nx);
    hipLaunchKernelGGL(cvt_f32_bf16, dim3(nwi / 1024), blk, 0, stream, w_in, winb, nwi);
    hipLaunchKernelGGL(cvt_f32_bf16, dim3(nwo / 1024), blk, 0, stream, w_out, woutb, nwo);
    // GEMM1: P = x @ w_in^T   (M=4096, N=6144, K=2048), bf16 out, BN=128 BK=64
    hipLaunchKernelGGL((gemm_bt<128, false>), dim3(48, 32, 1), blk, 0, stream, xObuf, winb, (void*)Pbuf, 6144, 2048);
    // Flash attention (x_bf16 dead now; O overwrites it), 512 blocks x 512 thr
    hipLaunchKernelGGL(attn_kernel, dim3(512, 1, 1), dim3(512, 1, 1), 0, stream, Pbuf, xObuf);
    // GEMM2: out = O @ w_out^T (M=4096, N=2048, K=2048), fp32 out, BN=64 BK=64
    hipLaunchKernelGGL((gemm_bt<64, true>), dim3(32, 32, 1), blk, 0, stream, xObuf, woutb, (void*)out, 2048, 2048);
}